// Round 11
// baseline (387.179 us; speedup 1.0000x reference)
//
#include <hip/hip_runtime.h>
#include <hip/hip_bf16.h>

#define NN 50000
#define EE 800000
#define EP 850000   // EE + NN self-loops
#define DD 128
#define NB 196      // ceil(NN/256)

typedef __attribute__((ext_vector_type(8))) short short8;
typedef __attribute__((ext_vector_type(4))) float f32x4;

__device__ __forceinline__ float bfLo(unsigned u){ return __uint_as_float(u << 16); }
__device__ __forceinline__ float bfHi(unsigned u){ return __uint_as_float(u & 0xffff0000u); }
__device__ __forceinline__ unsigned short f2bs(float x){
  __hip_bfloat16 h = __float2bfloat16(x);
  union { __hip_bfloat16 h; unsigned short u; } cv; cv.h = h; return cv.u;
}

// ---------------- prep: zero deg + scan control; pack W tiles (blocks 0..23);
// ---------------- W@a fragments (blocks 24..119) ----------------------------
__global__ void __launch_bounds__(256) prep_kernel(
    const float* __restrict__ W0, const float* __restrict__ as0, const float* __restrict__ ad0,
    const float* __restrict__ W1, const float* __restrict__ as1, const float* __restrict__ ad1,
    const float* __restrict__ W2, const float* __restrict__ as2, const float* __restrict__ ad2,
    unsigned short* __restrict__ Wmf, int* __restrict__ deg,
    int* __restrict__ ticket, int* __restrict__ bstat)
{
  const int tid = threadIdx.x;
  {
    int i = blockIdx.x*256 + tid;
    if (i < NN) deg[i] = 0;
  }
  if (blockIdx.x == 195){
    if (tid < NB) bstat[tid] = 0;
    if (tid == 0) ticket[0] = 0;
  }
  if (blockIdx.x < 24){
    // W reformat, tiles 0..31: Wmf[L][t=c*4+kb][lane][j] = W[kb*32+(lane>>4)*8+j][c*16+(lane&15)]
    const int L = blockIdx.x >> 3, seg = blockIdx.x & 7;
    const float* W = (L == 0) ? W0 : (L == 1) ? W1 : W2;
    int idx = seg*256 + tid;
    int t = idx >> 6, lane = idx & 63;
    int c = t >> 2, kb = t & 3;
    int m = lane & 15, quad = lane >> 4;
    unsigned short out[8];
    #pragma unroll
    for (int j = 0; j < 8; j++){
      int k = kb*32 + quad*8 + j;
      out[j] = f2bs(W[(size_t)k*DD + c*16 + m]);
    }
    *(uint4*)&Wmf[(((size_t)L*36 + t)*64 + lane)*8] = *(const uint4*)out;
  } else if (blockIdx.x < 120){
    // W@a_src / W@a_dst -> tile 8; one wave per (layer,k)
    const int q = blockIdx.x - 24;
    const int wIdx = q*4 + (tid >> 6);        // 0..383
    const int L = wIdx >> 7, k = wIdx & 127;
    const float *W, *as, *ad; int H;
    if (L == 0){ W = W0; as = as0; ad = ad0; H = 8; }
    else if (L == 1){ W = W1; as = as1; ad = ad1; H = 8; }
    else { W = W2; as = as2; ad = ad2; H = 1; }
    const int lane = tid & 63;
    const int c0 = lane*2;
    float w0 = W[(size_t)k*DD + c0];
    float w1 = W[(size_t)k*DD + c0 + 1];
    float ps = w0*as[c0] + w1*as[c0+1];
    float pd = w0*ad[c0] + w1*ad[c0+1];
    if (H == 8){
      #pragma unroll
      for (int off = 1; off <= 4; off <<= 1){
        ps += __shfl_xor(ps, off, 64);
        pd += __shfl_xor(pd, off, 64);
      }
    } else {
      #pragma unroll
      for (int off = 1; off <= 32; off <<= 1){
        ps += __shfl_xor(ps, off, 64);
        pd += __shfl_xor(pd, off, 64);
      }
    }
    int srcLane = (lane < 8) ? lane*8 : (lane < 16 ? (lane-8)*8 : 0);
    float vs = __shfl(ps, srcLane, 64);
    float vd = __shfl(pd, srcLane, 64);
    float myv;
    if (H == 8) myv = (lane < 8) ? vs : (lane < 16 ? vd : 0.f);
    else        myv = (lane == 0) ? ps : (lane == 1 ? pd : 0.f);
    const int kb = k >> 5, quad = (k >> 3) & 3, j = k & 7;
    if (lane < 16)
      Wmf[(((size_t)L*36 + 32 + kb)*64 + quad*16 + lane)*8 + j] = f2bs(myv);
  }
}

// ---------------- CSR build ----------------
__global__ void __launch_bounds__(256) hist_kernel(const int* __restrict__ ei, int* __restrict__ deg)
{
  int e = blockIdx.x*256 + threadIdx.x;
  if (e >= EP) return;
  int d = (e < EE) ? ei[EE + e] : e - EE;
  atomicAdd(&deg[d], 1);
}

// single-pass exclusive scan: ticket-ordered decoupled lookback.
// Ticket rank == scheduling order => rank r only spins on ranks < r (already resident).
__global__ void __launch_bounds__(256) scan_kernel(const int* __restrict__ deg,
    int* __restrict__ rowStart, int* __restrict__ cursor,
    int* __restrict__ ticket, int* __restrict__ bstat,
    int* __restrict__ bagg, int* __restrict__ bincl)
{
  __shared__ int buf[256];
  __shared__ int bid_s, prefix_s;
  const int tid = threadIdx.x;
  if (tid == 0) bid_s = atomicAdd(ticket, 1);
  __syncthreads();
  const int bid = bid_s;
  int i = bid*256 + tid;
  int v = (i < NN) ? deg[i] : 0;
  buf[tid] = v;
  __syncthreads();
  for (int off = 1; off < 256; off <<= 1){
    int t = (tid >= off) ? buf[tid - off] : 0;
    __syncthreads();
    buf[tid] += t;
    __syncthreads();
  }
  if (tid == 0){
    int total = buf[255];
    __hip_atomic_store(&bagg[bid], total, __ATOMIC_RELAXED, __HIP_MEMORY_SCOPE_AGENT);
    __hip_atomic_store(&bstat[bid], 1, __ATOMIC_RELEASE, __HIP_MEMORY_SCOPE_AGENT);
    int prefix = 0;
    for (int p = bid - 1; p >= 0; ){
      int st;
      do { st = __hip_atomic_load(&bstat[p], __ATOMIC_ACQUIRE, __HIP_MEMORY_SCOPE_AGENT); } while (st == 0);
      if (st == 2){
        prefix += __hip_atomic_load(&bincl[p], __ATOMIC_RELAXED, __HIP_MEMORY_SCOPE_AGENT);
        break;
      }
      prefix += __hip_atomic_load(&bagg[p], __ATOMIC_RELAXED, __HIP_MEMORY_SCOPE_AGENT);
      p--;
    }
    __hip_atomic_store(&bincl[bid], prefix + total, __ATOMIC_RELAXED, __HIP_MEMORY_SCOPE_AGENT);
    __hip_atomic_store(&bstat[bid], 2, __ATOMIC_RELEASE, __HIP_MEMORY_SCOPE_AGENT);
    prefix_s = prefix;
  }
  __syncthreads();
  int ex = buf[tid] - v + prefix_s;
  if (i < NN){ rowStart[i] = ex; cursor[i] = ex; }
  if (i == 0) rowStart[NN] = EP;
}

__global__ void __launch_bounds__(256) scatter_kernel(const int* __restrict__ ei,
    int* __restrict__ cursor, unsigned short* __restrict__ srcL)
{
  int e = blockIdx.x*256 + threadIdx.x;
  if (e >= EP) return;
  int s, d;
  if (e < EE){ s = ei[e]; d = ei[EE + e]; } else { s = d = e - EE; }
  int pos = atomicAdd(&cursor[d], 1);
  srcL[pos] = (unsigned short)s;
}

// ---------------- MFMA GEMM: h = x@W (bf16 out) + al dots via 9th col tile ----------------
template<bool XBF16, int H>
__global__ void __launch_bounds__(256) gemm_mfma_kernel(const void* __restrict__ Xv,
    const unsigned short* __restrict__ Wmf,
    unsigned short* __restrict__ Hout,
    float* __restrict__ alS, float* __restrict__ alD)
{
  __shared__ unsigned short wl[36*64*8];    // 36 KB = 2304 uint4
  const int tid = threadIdx.x;
  {
    const uint4* src = (const uint4*)Wmf;
    uint4* dst = (uint4*)wl;
    #pragma unroll
    for (int i = 0; i < 9; i++)
      dst[tid + i*256] = src[tid + i*256];
  }
  const int lane = tid & 63, wv = tid >> 6;
  const int r0 = blockIdx.x*64 + wv*16;
  const int m = lane & 15, quad = lane >> 4;
  const int row = r0 + m;
  const bool rowOK = row < NN;

  short8 a[4];
  if (XBF16){
    const short* Xb = (const short*)Xv;
    #pragma unroll
    for (int kb = 0; kb < 4; kb++){
      if (rowOK) a[kb] = *(const short8*)&Xb[(size_t)row*DD + kb*32 + quad*8];
      else       a[kb] = (short8){0,0,0,0,0,0,0,0};
    }
  } else {
    const float* Xf = (const float*)Xv;
    #pragma unroll
    for (int kb = 0; kb < 4; kb++){
      if (rowOK){
        float4 f0 = *(const float4*)&Xf[(size_t)row*DD + kb*32 + quad*8];
        float4 f1 = *(const float4*)&Xf[(size_t)row*DD + kb*32 + quad*8 + 4];
        union { short8 v; unsigned short u[8]; } cv;
        cv.u[0]=f2bs(f0.x); cv.u[1]=f2bs(f0.y); cv.u[2]=f2bs(f0.z); cv.u[3]=f2bs(f0.w);
        cv.u[4]=f2bs(f1.x); cv.u[5]=f2bs(f1.y); cv.u[6]=f2bs(f1.z); cv.u[7]=f2bs(f1.w);
        a[kb] = cv.v;
      } else a[kb] = (short8){0,0,0,0,0,0,0,0};
    }
  }
  __syncthreads();

  f32x4 acc[9];
  #pragma unroll
  for (int c = 0; c < 9; c++) acc[c] = (f32x4){0.f,0.f,0.f,0.f};
  #pragma unroll
  for (int c = 0; c < 9; c++){
    #pragma unroll
    for (int kb = 0; kb < 4; kb++){
      short8 b = *(const short8*)&wl[((c*4 + kb)*64 + lane)*8];
      acc[c] = __builtin_amdgcn_mfma_f32_16x16x32_bf16(a[kb], b, acc[c], 0, 0, 0);
    }
  }

  // h store: D layout col=lane&15, row=quad*4+reg
  #pragma unroll
  for (int c = 0; c < 8; c++){
    #pragma unroll
    for (int r = 0; r < 4; r++){
      int rw = r0 + quad*4 + r;
      if (rw < NN) Hout[(size_t)rw*DD + c*16 + m] = f2bs(acc[c][r]);
    }
  }
  #pragma unroll
  for (int r = 0; r < 4; r++){
    int rw = r0 + quad*4 + r;
    if (rw < NN){
      float v = acc[8][r];
      if (H == 8){
        if (m < 8) alS[rw*8 + m]       = v;
        else       alD[rw*8 + (m - 8)] = v;
      } else {
        if (m == 0)      alS[rw] = v;
        else if (m == 1) alD[rw] = v;
      }
    }
  }
}

// ---------------- fused: per-dst softmax + gather-aggregate + bias + LN (+ELU) ----------------
// PAIRED: 32 lanes per dst (4 channels/lane), 2 dsts per wave -> per-edge wave
// overhead (shfl, alS broadcast, exp, addr) amortized over 2 edges at once.
template<int H, bool FINAL>
__global__ void __launch_bounds__(256) aggln_kernel(
    const int* __restrict__ rowStart, const unsigned short* __restrict__ srcL,
    const float* __restrict__ alS, const float* __restrict__ alD,
    const unsigned short* __restrict__ hB,
    const float* __restrict__ b, const float* __restrict__ g, const float* __restrict__ be,
    void* __restrict__ outv)
{
  const int l32 = threadIdx.x & 31;
  const int d   = blockIdx.x*8 + (threadIdx.x >> 5);   // 8 dsts/block, exact cover
  const int c0  = l32*4;
  const int hd  = (H == 8) ? (l32 >> 2) : 0;
  const int start = rowStart[d], end = rowStart[d+1];
  const int myLen = end - start;
  const int otherLen = __shfl_xor(myLen, 32, 64);
  const int maxLen = max(myLen, otherLen);
  const float aldv = alD[d*H + hd];

  float ssum = 0.f, a0 = 0.f, a1 = 0.f, a2 = 0.f, a3 = 0.f;
  for (int base = 0; base < maxLen; base += 32){
    int myS = (base + l32 < myLen) ? (int)srcL[start + base + l32] : 0;
    int cnt = myLen - base; cnt = cnt < 0 ? 0 : (cnt > 32 ? 32 : cnt);
    int cntO = __shfl_xor(cnt, 32, 64);
    int jmax = max(cnt, cntO);
    int j = 0;
    for (; j + 2 <= jmax; j += 2){
      int sA = __shfl(myS, j,   32);
      int sB = __shfl(myS, j+1, 32);
      uint2 hA = *(const uint2*)&hB[(size_t)sA*DD + c0];
      uint2 hBv = *(const uint2*)&hB[(size_t)sB*DD + c0];
      float eA = alS[sA*H + hd] + aldv;
      float eB = alS[sB*H + hd] + aldv;
      eA = fmaxf(eA, 0.2f*eA);                // leaky (slope<1 => max identity)
      eB = fmaxf(eB, 0.2f*eB);
      float wA = __expf(eA);
      float wB = __expf(eB);
      wA = (j   < cnt) ? wA : 0.f;
      wB = (j+1 < cnt) ? wB : 0.f;
      ssum += wA + wB;
      a0 = fmaf(bfLo(hA.x), wA, a0);  a1 = fmaf(bfHi(hA.x), wA, a1);
      a2 = fmaf(bfLo(hA.y), wA, a2);  a3 = fmaf(bfHi(hA.y), wA, a3);
      a0 = fmaf(bfLo(hBv.x), wB, a0); a1 = fmaf(bfHi(hBv.x), wB, a1);
      a2 = fmaf(bfLo(hBv.y), wB, a2); a3 = fmaf(bfHi(hBv.y), wB, a3);
    }
    if (j < jmax){
      int sA = __shfl(myS, j, 32);
      uint2 hA = *(const uint2*)&hB[(size_t)sA*DD + c0];
      float eA = alS[sA*H + hd] + aldv;
      eA = fmaxf(eA, 0.2f*eA);
      float wA = __expf(eA);
      wA = (j < cnt) ? wA : 0.f;
      ssum += wA;
      a0 = fmaf(bfLo(hA.x), wA, a0);  a1 = fmaf(bfHi(hA.x), wA, a1);
      a2 = fmaf(bfLo(hA.y), wA, a2);  a3 = fmaf(bfHi(hA.y), wA, a3);
    }
  }
  const float sinv = 1.f / ssum;

  // bias + LayerNorm across the 32-lane half's 128 channels
  float v0 = a0*sinv + b[c0],   v1 = a1*sinv + b[c0+1];
  float v2 = a2*sinv + b[c0+2], v3 = a3*sinv + b[c0+3];
  float s2 = (v0 + v1) + (v2 + v3);
  #pragma unroll
  for (int off = 16; off >= 1; off >>= 1) s2 += __shfl_xor(s2, off, 32);
  float mu = s2 * (1.0f/128.0f);
  float d0 = v0 - mu, d1 = v1 - mu, d2 = v2 - mu, d3 = v3 - mu;
  float q = (d0*d0 + d1*d1) + (d2*d2 + d3*d3);
  #pragma unroll
  for (int off = 16; off >= 1; off >>= 1) q += __shfl_xor(q, off, 32);
  float r = rsqrtf(q*(1.0f/128.0f) + 1e-5f);
  float y0 = d0*r*g[c0]   + be[c0];
  float y1 = d1*r*g[c0+1] + be[c0+1];
  float y2 = d2*r*g[c0+2] + be[c0+2];
  float y3 = d3*r*g[c0+3] + be[c0+3];
  if (FINAL){
    *(float4*)&((float*)outv)[(size_t)d*DD + c0] = make_float4(y0, y1, y2, y3);
  } else {
    y0 = y0 > 0.f ? y0 : __expf(y0) - 1.f;   // ELU
    y1 = y1 > 0.f ? y1 : __expf(y1) - 1.f;
    y2 = y2 > 0.f ? y2 : __expf(y2) - 1.f;
    y3 = y3 > 0.f ? y3 : __expf(y3) - 1.f;
    uint2 o;
    o.x = (unsigned)f2bs(y0) | ((unsigned)f2bs(y1) << 16);
    o.y = (unsigned)f2bs(y2) | ((unsigned)f2bs(y3) << 16);
    *(uint2*)&((unsigned short*)outv)[(size_t)d*DD + c0] = o;
  }
}

// ---------------- host-side layer driver ----------------
template<bool XBF16, int H, bool FINAL>
static void run_layer(const void* x, const unsigned short* WmfL,
                      const float* b, const float* g, const float* be,
                      const int* rowStart, const unsigned short* srcL,
                      unsigned short* hB, float* alS, float* alD,
                      void* outv, hipStream_t stream)
{
  gemm_mfma_kernel<XBF16, H><<<782, 256, 0, stream>>>(x, WmfL, hB, alS, alD);
  aggln_kernel<H, FINAL><<<6250, 256, 0, stream>>>(rowStart, srcL, alS, alD, hB,
                                                   b, g, be, outv);
}

extern "C" void kernel_launch(void* const* d_in, const int* in_sizes, int n_in,
                              void* d_out, int out_size, void* d_ws, size_t ws_size,
                              hipStream_t stream)
{
  // ws layout (~31.5 MB)
  char* w = (char*)d_ws;
  unsigned short* accB = (unsigned short*)w;     w += (size_t)NN*DD*2;   // 12.8 MB
  unsigned short* hB   = (unsigned short*)w;     w += (size_t)NN*DD*2;   // 12.8 MB
  float* alS      = (float*)w;                   w += (size_t)NN*8*4;    // 1.6 MB
  float* alD      = (float*)w;                   w += (size_t)NN*8*4;    // 1.6 MB
  unsigned short* Wmf = (unsigned short*)w;      w += (size_t)3*36*64*8*2; // 216 KB
  int*   deg      = (int*)w;                     w += (size_t)NN*4;      // 200 KB
  int*   rowStart = (int*)w;                     w += (size_t)(NN+1)*4;  // 200 KB
  int*   cursor   = (int*)w;                     w += (size_t)NN*4;      // 200 KB
  int*   ticket   = (int*)w;                     w += 256;
  int*   bstat    = (int*)w;                     w += (size_t)NB*4;
  int*   bagg     = (int*)w;                     w += (size_t)NB*4;
  int*   bincl    = (int*)w;                     w += (size_t)NB*4;
  unsigned short* srcL = (unsigned short*)w;     w += (size_t)EP*2;      // 1.7 MB
  if (ws_size < (size_t)(w - (char*)d_ws)) return;

  const float* x  = (const float*)d_in[0];
  const int*   ei = (const int*)d_in[1];
  const float *W0=(const float*)d_in[2], *as0=(const float*)d_in[3], *ad0=(const float*)d_in[4];
  const float *b0=(const float*)d_in[5], *g0=(const float*)d_in[6], *be0=(const float*)d_in[7];
  const float *W1=(const float*)d_in[8], *as1=(const float*)d_in[9], *ad1=(const float*)d_in[10];
  const float *b1=(const float*)d_in[11],*g1=(const float*)d_in[12],*be1=(const float*)d_in[13];
  const float *W2=(const float*)d_in[14],*as2=(const float*)d_in[15],*ad2=(const float*)d_in[16];
  const float *b2=(const float*)d_in[17],*g2=(const float*)d_in[18],*be2=(const float*)d_in[19];

  prep_kernel<<<NB, 256, 0, stream>>>(W0, as0, ad0, W1, as1, ad1, W2, as2, ad2,
                                      Wmf, deg, ticket, bstat);
  hist_kernel<<<(EP + 255)/256, 256, 0, stream>>>(ei, deg);
  scan_kernel<<<NB, 256, 0, stream>>>(deg, rowStart, cursor, ticket, bstat, bagg, bincl);
  scatter_kernel<<<(EP + 255)/256, 256, 0, stream>>>(ei, cursor, srcL);

  // layer 0: x = f32 input, 8 heads, ELU -> accB (bf16)
  run_layer<false, 8, false>(x,    Wmf,            b0, g0, be0,
                             rowStart, srcL, hB, alS, alD, accB, stream);
  // layer 1: x = accB (bf16), 8 heads, ELU -> accB
  run_layer<true, 8, false>(accB, Wmf + (size_t)36*64*8,   b1, g1, be1,
                             rowStart, srcL, hB, alS, alD, accB, stream);
  // layer 2: x = accB (bf16), 1 head, LN only -> d_out (f32)
  run_layer<true, 1, true>(accB, Wmf + (size_t)2*36*64*8,  b2, g2, be2,
                             rowStart, srcL, hB, alS, alD, d_out, stream);
}